// Round 1
// baseline (190.147 us; speedup 1.0000x reference)
//
#include <hip/hip_runtime.h>
#include <math.h>

#define EPS32 1.1920929e-07f

constexpr int B = 16, C = 80, H = 128, W = 128, NBOX = 64;
constexpr int NCORR = B * NBOX;          // 1024 correction blocks (one per box)
constexpr int NSTREAM = 2048;            // streaming blocks
constexpr int NTOT = B * C * H * W;      // 20,971,520
constexpr int NV4 = NTOT / 4;            // 5,242,880 float4s

__device__ __forceinline__ float f0_term(float p) {
    // ct == 0 branch of the focal loss: -log(1-p+1e-12) * p^2
    return -__logf(1.0f - p + 1e-12f) * p * p;
}

// Block-wide sum; result valid on thread 0 only. Contains one __syncthreads.
__device__ __forceinline__ float block_reduce_add(float v, float* sred) {
    #pragma unroll
    for (int off = 32; off > 0; off >>= 1)
        v += __shfl_down(v, off, 64);
    int lane = threadIdx.x & 63;
    int wid  = threadIdx.x >> 6;
    if (lane == 0) sred[wid] = v;
    __syncthreads();
    if (threadIdx.x == 0) {
        float s = sred[0];
        #pragma unroll
        for (int i = 1; i < 4; ++i) s += sred[i];
        return s;
    }
    return 0.0f;
}

// acc layout (floats in d_ws): [0]=center_sum  [1]=S_wh  [2]=S_off  [3]=af
__global__ __launch_bounds__(256) void fused_kernel(
    const float* __restrict__ cp, const float* __restrict__ whp,
    const float* __restrict__ ofp, const float* __restrict__ boxes,
    const int* __restrict__ labels, float* __restrict__ acc)
{
    __shared__ float sred[4];
    const int t = threadIdx.x;

    if (blockIdx.x < (unsigned)NCORR) {
        // ---------- sparse correction block: one box ----------
        __shared__ int   scx[NBOX], scy[NBOX], sre[NBOX], slab[NBOX], slist[NBOX];
        __shared__ float sinv[NBOX], ssw[NBOX], ssh[NBOX], sox[NBOX], soy[NBOX];
        __shared__ int   nlist;
        const int k = blockIdx.x;
        const int b = k >> 6;
        const int n = k & 63;

        if (t < NBOX) {
            const float* bx = boxes + ((b * NBOX + t) << 2);
            float x1 = bx[0], y1 = bx[1], x2 = bx[2], y2 = bx[3];
            // w_ratio = h_ratio = 128/512 = 0.25 (exact power-of-2 scalings)
            float cx = (x1 + x2) * 0.25f * 0.5f;
            float cy = (y1 + y2) * 0.25f * 0.5f;
            int cxi = (int)floorf(cx);
            int cyi = (int)floorf(cy);
            float sw = (x2 - x1) * 0.25f;
            float sh = (y2 - y1) * 0.25f;
            // gaussian radius, min_overlap = 0.3 (h = sh, w = sw)
            float h = sh, w = sw;
            float b1 = h + w;
            float c1 = w * h * 0.7f / 1.3f;
            float r1 = (b1 - sqrtf(b1 * b1 - 4.0f * c1)) * 0.5f;
            float b2 = 2.0f * (h + w);
            float c2 = 0.7f * w * h;
            float r2 = (b2 - sqrtf(b2 * b2 - 16.0f * c2)) * 0.125f;
            float b3 = -0.6f * (h + w);
            float c3 = -0.7f * w * h;
            float r3 = (b3 + sqrtf(b3 * b3 - 4.8f * c3)) / 2.4f;
            float r = fminf(fminf(r1, r2), r3);
            int rad = (int)fmaxf(0.0f, floorf(r));
            float d = (float)(2 * rad + 1);
            float sigma2 = 2.0f * d / 6.0f * (d / 6.0f);
            scx[t] = cxi; scy[t] = cyi;
            sre[t] = rad < 16 ? rad : 16;     // window clamp (dx,dy grid is ±16)
            slab[t] = labels[b * NBOX + t];
            sinv[t] = 1.0f / sigma2;
            ssw[t] = sw; ssh[t] = sh;
            sox[t] = cx - (float)cxi; soy[t] = cy - (float)cyi;
        }
        __syncthreads();

        if (t == 0) {
            // candidate list: same-batch boxes with the same label as box n
            int c = slab[n], L = 0;
            for (int m = 0; m < NBOX; ++m) if (slab[m] == c) slist[L++] = m;
            nlist = L;
            // wh/offset: scatter-set => last write (max index) wins per (cyi,cxi)
            bool winner = true;
            for (int m = n + 1; m < NBOX; ++m)
                if (scx[m] == scx[n] && scy[m] == scy[n]) { winner = false; break; }
            if (winner) {
                int cxi = scx[n], cyi = scy[n];
                int i0 = ((b * 2 + 0) * H + cyi) * W + cxi;
                int i1 = ((b * 2 + 1) * H + cyi) * W + cxi;
                float swh = fabsf(whp[i0] - ssw[n]) + fabsf(whp[i1] - ssh[n]);
                float sof = fabsf(ofp[i0] - sox[n]) + fabsf(ofp[i1] - soy[n]);
                atomicAdd(acc + 1, swh);
                atomicAdd(acc + 2, sof);
            }
            // af: count distinct (label, cyi, cxi) => first occurrence
            bool first = true;
            for (int m = 0; m < n; ++m)
                if (slab[m] == slab[n] && scx[m] == scx[n] && scy[m] == scy[n]) { first = false; break; }
            if (first) atomicAdd(acc + 3, 1.0f);
        }
        __syncthreads();

        const int c  = slab[n];
        const int R  = sre[n];
        const int Wd = 2 * R + 1;
        const int cells = Wd * Wd;
        const int cx0 = scx[n], cy0 = scy[n];
        const int L = nlist;
        float corr = 0.0f;
        for (int cell = t; cell < cells; cell += 256) {
            int dy = cell / Wd - R;
            int dx = cell - (dy + R) * Wd - R;
            int y = cy0 + dy, x = cx0 + dx;
            if ((unsigned)y >= (unsigned)H || (unsigned)x >= (unsigned)W) continue;
            // ct = max gaussian over covering same-label boxes; owner = min index
            int minm = NBOX;
            float ct = 0.0f;
            for (int i = 0; i < L; ++i) {
                int m = slist[i];
                int ddx = x - scx[m], ddy = y - scy[m];
                int re = sre[m];
                if (ddx > re || ddx < -re || ddy > re || ddy < -re) continue;
                if (m < minm) minm = m;
                float d2 = (float)(ddx * ddx + ddy * ddy);
                float kv = (d2 == 0.0f) ? 1.0f : __expf(-d2 * sinv[m]);
                if (kv < EPS32) kv = 0.0f;          // reference EPS cut
                ct = fmaxf(ct, kv);
            }
            if (minm != n) continue;                 // another block owns this cell
            float p = cp[((b * C + c) * H + y) * W + x];
            float lt = __logf(1.0f - p + 1e-12f);
            float omc = 1.0f - ct;
            float w2 = omc * omc;
            float w4 = w2 * w2;
            // f(p,ct) - f0(p):  neg-weight delta + pos term at exact centers
            float val = -lt * p * p * (w4 - 1.0f);
            if (ct == 1.0f) {
                float q = 1.0f - p;
                val += -__logf(p + 1e-12f) * q * q;
            }
            corr += val;
        }
        float s = block_reduce_add(corr, sred);
        if (t == 0) atomicAdd(acc + 0, s);
    } else {
        // ---------- dense streaming block: sum f0 over all cells ----------
        const float4* cp4 = (const float4*)cp;
        int i = (blockIdx.x - NCORR) * 256 + t;
        float s = 0.0f;
        for (; i < NV4; i += NSTREAM * 256) {
            float4 v = cp4[i];
            s += f0_term(v.x) + f0_term(v.y) + f0_term(v.z) + f0_term(v.w);
        }
        float tot = block_reduce_add(s, sred);
        if (t == 0) atomicAdd(acc + 0, tot);
    }
}

__global__ void finalize_kernel(const float* __restrict__ acc, float* __restrict__ out) {
    float af = fmaxf(1.0f, acc[3]);
    float loss = acc[0] / (af + EPS32)
               + 0.1f * acc[1] / (af * 2.0f + EPS32)
               + acc[2] / (af * 2.0f + EPS32);
    out[0] = loss;
}

extern "C" void kernel_launch(void* const* d_in, const int* in_sizes, int n_in,
                              void* d_out, int out_size, void* d_ws, size_t ws_size,
                              hipStream_t stream) {
    const float* cp     = (const float*)d_in[0];   // center_pred (16,80,128,128)
    const float* whp    = (const float*)d_in[1];   // wh_pred     (16,2,128,128)
    const float* ofp    = (const float*)d_in[2];   // offset_pred (16,2,128,128)
    const float* boxes  = (const float*)d_in[3];   // (16,64,4)
    const int*   labels = (const int*)d_in[4];     // (16,64)
    float* acc = (float*)d_ws;                     // 4 floats of scratch

    hipMemsetAsync(acc, 0, 4 * sizeof(float), stream);
    fused_kernel<<<NCORR + NSTREAM, 256, 0, stream>>>(cp, whp, ofp, boxes, labels, acc);
    finalize_kernel<<<1, 1, 0, stream>>>(acc, (float*)d_out);
}

// Round 2
// 130.325 us; speedup vs baseline: 1.4590x; 1.4590x over previous
//
#include <hip/hip_runtime.h>
#include <math.h>

#define EPS32 1.1920929e-07f

constexpr int B = 16, C = 80, H = 128, W = 128, NBOX = 64;
constexpr int NCORR = B * NBOX;          // 1024 correction blocks (one per box)
constexpr int NSTREAM = 1024;            // streaming blocks
constexpr int NBLK = NCORR + NSTREAM;    // 2048 total = 8 blocks/CU, one round
constexpr int NTOT = B * C * H * W;      // 20,971,520
constexpr int NV4 = NTOT / 4;            // 5,242,880 float4s
constexpr int SSTRIDE = NSTREAM * 256;   // 262,144 -> exactly 20 iters/thread

__device__ __forceinline__ float f0_term(float p) {
    // ct == 0 branch of the focal loss: -log(1-p+1e-12) * p^2
    return -__logf(1.0f - p + 1e-12f) * p * p;
}

// Block-wide sum; result valid on thread 0 only. Contains one __syncthreads.
__device__ __forceinline__ float block_reduce_add(float v, float* sred) {
    #pragma unroll
    for (int off = 32; off > 0; off >>= 1)
        v += __shfl_down(v, off, 64);
    int lane = threadIdx.x & 63;
    int wid  = threadIdx.x >> 6;
    if (lane == 0) sred[wid] = v;
    __syncthreads();
    if (threadIdx.x == 0) {
        float s = sred[0];
        #pragma unroll
        for (int i = 1; i < 4; ++i) s += sred[i];
        return s;
    }
    return 0.0f;
}

// Each block writes one float4 partial {center_sum, wh_sum, off_sum, af} to
// ws4[blockIdx.x]. NO global atomics (same-line atomics serialized ~90us in R1).
__global__ __launch_bounds__(256) void fused_kernel(
    const float* __restrict__ cp, const float* __restrict__ whp,
    const float* __restrict__ ofp, const float* __restrict__ boxes,
    const int* __restrict__ labels, float4* __restrict__ ws4)
{
    __shared__ float sred[4];
    const int t = threadIdx.x;
    float my_wh = 0.0f, my_of = 0.0f, my_af = 0.0f;
    float center = 0.0f;

    if (blockIdx.x < (unsigned)NCORR) {
        // ---------- sparse correction block: one box ----------
        __shared__ int   scx[NBOX], scy[NBOX], sre[NBOX], slab[NBOX], slist[NBOX];
        __shared__ float sinv[NBOX], ssw[NBOX], ssh[NBOX], sox[NBOX], soy[NBOX];
        __shared__ int   nlist;
        const int k = blockIdx.x;
        const int b = k >> 6;
        const int n = k & 63;

        if (t < NBOX) {
            const float* bx = boxes + ((b * NBOX + t) << 2);
            float x1 = bx[0], y1 = bx[1], x2 = bx[2], y2 = bx[3];
            // w_ratio = h_ratio = 128/512 = 0.25 (exact power-of-2 scalings)
            float cx = (x1 + x2) * 0.25f * 0.5f;
            float cy = (y1 + y2) * 0.25f * 0.5f;
            int cxi = (int)floorf(cx);
            int cyi = (int)floorf(cy);
            float sw = (x2 - x1) * 0.25f;
            float sh = (y2 - y1) * 0.25f;
            // gaussian radius, min_overlap = 0.3 (h = sh, w = sw)
            float h = sh, w = sw;
            float b1 = h + w;
            float c1 = w * h * 0.7f / 1.3f;
            float r1 = (b1 - sqrtf(b1 * b1 - 4.0f * c1)) * 0.5f;
            float b2 = 2.0f * (h + w);
            float c2 = 0.7f * w * h;
            float r2 = (b2 - sqrtf(b2 * b2 - 16.0f * c2)) * 0.125f;
            float b3 = -0.6f * (h + w);
            float c3 = -0.7f * w * h;
            float r3 = (b3 + sqrtf(b3 * b3 - 4.8f * c3)) / 2.4f;
            float r = fminf(fminf(r1, r2), r3);
            int rad = (int)fmaxf(0.0f, floorf(r));
            float d = (float)(2 * rad + 1);
            float sigma2 = 2.0f * d / 6.0f * (d / 6.0f);
            scx[t] = cxi; scy[t] = cyi;
            sre[t] = rad < 16 ? rad : 16;     // window clamp (dx,dy grid is ±16)
            slab[t] = labels[b * NBOX + t];
            sinv[t] = 1.0f / sigma2;
            ssw[t] = sw; ssh[t] = sh;
            sox[t] = cx - (float)cxi; soy[t] = cy - (float)cyi;
        }
        __syncthreads();

        if (t == 0) {
            // candidate list: same-batch boxes with the same label as box n
            int c = slab[n], L = 0;
            for (int m = 0; m < NBOX; ++m) if (slab[m] == c) slist[L++] = m;
            nlist = L;
            // wh/offset: scatter-set => last write (max index) wins per (cyi,cxi)
            bool winner = true;
            for (int m = n + 1; m < NBOX; ++m)
                if (scx[m] == scx[n] && scy[m] == scy[n]) { winner = false; break; }
            if (winner) {
                int cxi = scx[n], cyi = scy[n];
                int i0 = ((b * 2 + 0) * H + cyi) * W + cxi;
                int i1 = ((b * 2 + 1) * H + cyi) * W + cxi;
                my_wh = fabsf(whp[i0] - ssw[n]) + fabsf(whp[i1] - ssh[n]);
                my_of = fabsf(ofp[i0] - sox[n]) + fabsf(ofp[i1] - soy[n]);
            }
            // af: count distinct (label, cyi, cxi) => first occurrence
            bool first = true;
            for (int m = 0; m < n; ++m)
                if (slab[m] == slab[n] && scx[m] == scx[n] && scy[m] == scy[n]) { first = false; break; }
            if (first) my_af = 1.0f;
        }
        __syncthreads();

        const int c  = slab[n];
        const int R  = sre[n];
        const int Wd = 2 * R + 1;
        const int cells = Wd * Wd;
        const int cx0 = scx[n], cy0 = scy[n];
        const int L = nlist;
        float corr = 0.0f;
        for (int cell = t; cell < cells; cell += 256) {
            int dy = cell / Wd - R;
            int dx = cell - (dy + R) * Wd - R;
            int y = cy0 + dy, x = cx0 + dx;
            if ((unsigned)y >= (unsigned)H || (unsigned)x >= (unsigned)W) continue;
            // ct = max gaussian over covering same-label boxes; owner = min index
            int minm = NBOX;
            float ct = 0.0f;
            for (int i = 0; i < L; ++i) {
                int m = slist[i];
                int ddx = x - scx[m], ddy = y - scy[m];
                int re = sre[m];
                if (ddx > re || ddx < -re || ddy > re || ddy < -re) continue;
                if (m < minm) minm = m;
                float d2 = (float)(ddx * ddx + ddy * ddy);
                float kv = (d2 == 0.0f) ? 1.0f : __expf(-d2 * sinv[m]);
                if (kv < EPS32) kv = 0.0f;          // reference EPS cut
                ct = fmaxf(ct, kv);
            }
            if (minm != n) continue;                 // another block owns this cell
            float p = cp[((b * C + c) * H + y) * W + x];
            float lt = __logf(1.0f - p + 1e-12f);
            float omc = 1.0f - ct;
            float w2 = omc * omc;
            float w4 = w2 * w2;
            // f(p,ct) - f0(p):  neg-weight delta + pos term at exact centers
            float val = -lt * p * p * (w4 - 1.0f);
            if (ct == 1.0f) {
                float q = 1.0f - p;
                val += -__logf(p + 1e-12f) * q * q;
            }
            corr += val;
        }
        center = block_reduce_add(corr, sred);
    } else {
        // ---------- dense streaming block: sum f0 over all cells ----------
        const float4* cp4 = (const float4*)cp;
        const int base = (blockIdx.x - NCORR) * 256 + t;
        float s0 = 0.0f, s1 = 0.0f, s2 = 0.0f, s3 = 0.0f;
        #pragma unroll 1
        for (int j = 0; j < 20; j += 4) {
            float4 a = cp4[base + (j + 0) * SSTRIDE];
            float4 b = cp4[base + (j + 1) * SSTRIDE];
            float4 c = cp4[base + (j + 2) * SSTRIDE];
            float4 d = cp4[base + (j + 3) * SSTRIDE];
            s0 += f0_term(a.x) + f0_term(a.y) + f0_term(a.z) + f0_term(a.w);
            s1 += f0_term(b.x) + f0_term(b.y) + f0_term(b.z) + f0_term(b.w);
            s2 += f0_term(c.x) + f0_term(c.y) + f0_term(c.z) + f0_term(c.w);
            s3 += f0_term(d.x) + f0_term(d.y) + f0_term(d.z) + f0_term(d.w);
        }
        center = block_reduce_add((s0 + s1) + (s2 + s3), sred);
    }

    if (t == 0) {
        float4 out;
        out.x = center; out.y = my_wh; out.z = my_of; out.w = my_af;
        ws4[blockIdx.x] = out;
    }
}

__global__ __launch_bounds__(256) void finalize_kernel(
    const float4* __restrict__ ws4, float* __restrict__ out)
{
    __shared__ float sred[4];
    float c = 0.0f, wh = 0.0f, of = 0.0f, af = 0.0f;
    for (int i = threadIdx.x; i < NBLK; i += 256) {
        float4 v = ws4[i];
        c += v.x; wh += v.y; of += v.z; af += v.w;
    }
    float cs = block_reduce_add(c, sred);  __syncthreads();
    float ws = block_reduce_add(wh, sred); __syncthreads();
    float os = block_reduce_add(of, sred); __syncthreads();
    float as = block_reduce_add(af, sred);
    if (threadIdx.x == 0) {
        float a = fmaxf(1.0f, as);
        out[0] = cs / (a + EPS32)
               + 0.1f * ws / (a * 2.0f + EPS32)
               + os / (a * 2.0f + EPS32);
    }
}

extern "C" void kernel_launch(void* const* d_in, const int* in_sizes, int n_in,
                              void* d_out, int out_size, void* d_ws, size_t ws_size,
                              hipStream_t stream) {
    const float* cp     = (const float*)d_in[0];   // center_pred (16,80,128,128)
    const float* whp    = (const float*)d_in[1];   // wh_pred     (16,2,128,128)
    const float* ofp    = (const float*)d_in[2];   // offset_pred (16,2,128,128)
    const float* boxes  = (const float*)d_in[3];   // (16,64,4)
    const int*   labels = (const int*)d_in[4];     // (16,64)
    float4* ws4 = (float4*)d_ws;                   // NBLK float4 partials (32 KB)

    fused_kernel<<<NBLK, 256, 0, stream>>>(cp, whp, ofp, boxes, labels, ws4);
    finalize_kernel<<<1, 256, 0, stream>>>(ws4, (float*)d_out);
}